// Round 6
// baseline (2725.818 us; speedup 1.0000x reference)
//
#include <hip/hip_runtime.h>

#define F_IN 500
#define HH 32
#define DD 64
#define LN_EPS 1e-6f
#define QCAP 100000     // slots per (cohort, writer-class) queue

typedef float f32x4 __attribute__((ext_vector_type(4)));
typedef _Float16 f16x8 __attribute__((ext_vector_type(8)));
typedef _Float16 h16;

// ---------------------------------------------------------------------------
// prep: W1T f16 [32 j][512 k] (zero-padded k>=500), W2T f16 [64 d][32 j]
// ---------------------------------------------------------------------------
__global__ __launch_bounds__(256)
void prep_k(const float* __restrict__ W1, const float* __restrict__ W2,
            h16* __restrict__ w1t, h16* __restrict__ w2t)
{
    int i = blockIdx.x * 256 + threadIdx.x;
    if (i < 32 * 512) {
        int j = i >> 9, k = i & 511;
        w1t[i] = (k < F_IN) ? (h16)W1[k * HH + j] : (h16)0.f;
    }
    int i2 = i - 32 * 512;
    if (i2 >= 0 && i2 < 64 * 32) {
        int d = i2 >> 5, j = i2 & 31;
        w2t[i2] = (h16)W2[j * DD + d];
    }
}

// ---------------------------------------------------------------------------
// Encoder via MFMA 16x16x32 f16. Wave = 16 rows. No block barriers, no big
// LDS: x A-frags + W1T/W2T B-frags loaded straight to VGPRs.
// A layout: lane holds A[l&15][(l>>4)*8..+8]; B: B-rows = cols via W^T tables;
// C/D: col=l&15, row=(l>>4)*4+reg (m89-verified).
// ---------------------------------------------------------------------------
__global__ __launch_bounds__(256)
void encoder_k(const float* __restrict__ x,
               const h16* __restrict__ w1t, const float* __restrict__ b1,
               const float* __restrict__ gamma, const float* __restrict__ beta,
               const h16* __restrict__ w2t, const float* __restrict__ b2,
               float* __restrict__ h0, int N)
{
    __shared__ h16 hbuf[4][512];        // per-wave 16x32 transpose buf (slot-swizzled)

    const int t = threadIdx.x;
    const int w = t >> 6, l = t & 63;
    const int c0 = l & 15, kg = l >> 4;
    const int gr0 = (blockIdx.x * 4 + w) * 16;
    int rowA = gr0 + c0; if (rowA >= N) rowA = N - 1;
    const float* xr = x + (size_t)rowA * F_IN;

    float b1a = b1[c0], b1b = b1[c0 + 16];
    f32x4 acc0 = {b1a, b1a, b1a, b1a};
    f32x4 acc1 = {b1b, b1b, b1b, b1b};

    const h16* w1a = w1t + c0 * 512 + kg * 8;
    const h16* w1b = w1a + 16 * 512;

    #pragma unroll 3
    for (int ks = 0; ks < 15; ++ks) {
        const int k0 = ks * 32;
        f32x4 xa = *(const f32x4*)(xr + k0 + kg * 8);
        f32x4 xb = *(const f32x4*)(xr + k0 + kg * 8 + 4);
        f16x8 af;
        af[0] = (h16)xa[0]; af[1] = (h16)xa[1]; af[2] = (h16)xa[2]; af[3] = (h16)xa[3];
        af[4] = (h16)xb[0]; af[5] = (h16)xb[1]; af[6] = (h16)xb[2]; af[7] = (h16)xb[3];
        f16x8 bf0 = *(const f16x8*)(w1a + k0);
        f16x8 bf1 = *(const f16x8*)(w1b + k0);
        acc0 = __builtin_amdgcn_mfma_f32_16x16x32_f16(af, bf0, acc0, 0, 0, 0);
        acc1 = __builtin_amdgcn_mfma_f32_16x16x32_f16(af, bf1, acc1, 0, 0, 0);
    }
    {   // tail k=480..511: A masked (B rows are zero-padded past 500 anyway)
        f16x8 af;
        #pragma unroll
        for (int e = 0; e < 8; ++e) {
            int k = 480 + kg * 8 + e;
            af[e] = (k < F_IN) ? (h16)xr[k] : (h16)0.f;
        }
        f16x8 bf0 = *(const f16x8*)(w1a + 480);
        f16x8 bf1 = *(const f16x8*)(w1b + 480);
        acc0 = __builtin_amdgcn_mfma_f32_16x16x32_f16(af, bf0, acc0, 0, 0, 0);
        acc1 = __builtin_amdgcn_mfma_f32_16x16x32_f16(af, bf1, acc1, 0, 0, 0);
    }

    // ---- LayerNorm + relu in C-layout; write f16 transpose buffer ----
    float g0 = gamma[c0], g1 = gamma[c0 + 16];
    float be0 = beta[c0], be1 = beta[c0 + 16];
    h16* hb = hbuf[w];
    #pragma unroll
    for (int i = 0; i < 4; ++i) {
        float a0 = acc0[i], a1 = acc1[i];
        float s = a0 + a1;
        s += __shfl_xor(s, 1); s += __shfl_xor(s, 2);
        s += __shfl_xor(s, 4); s += __shfl_xor(s, 8);
        float mu = s * (1.0f / 32.0f);
        float d0 = a0 - mu, d1 = a1 - mu;
        float vv = d0 * d0 + d1 * d1;
        vv += __shfl_xor(vv, 1); vv += __shfl_xor(vv, 2);
        vv += __shfl_xor(vv, 4); vv += __shfl_xor(vv, 8);
        float is = rsqrtf(vv * (1.0f / 32.0f) + LN_EPS);
        float h0v = fmaxf(fmaf(d0 * is, g0, be0), 0.f);
        float h1v = fmaxf(fmaf(d1 * is, g1, be1), 0.f);
        int r = kg * 4 + i;                 // r&3 == i
        hb[r * 32 + ((((c0 >> 3) ^ i) & 3) << 3) + (c0 & 7)] = (h16)h0v;
        hb[r * 32 + ((((2 + (c0 >> 3)) ^ i) & 3) << 3) + (c0 & 7)] = (h16)h1v;
    }
    asm volatile("s_waitcnt lgkmcnt(0)" ::: "memory");
    __builtin_amdgcn_sched_barrier(0);

    // A-frag for GEMM2 (swizzled read: 4-way max, 1 instr)
    f16x8 ah = *(const f16x8*)(hb + c0 * 32 + (((kg ^ (c0 & 3)) & 3) << 3));

    // ---- GEMM2: 4 col-tiles of 16 ----
    f32x4 oc[4];
    #pragma unroll
    for (int tl = 0; tl < 4; ++tl) {
        float bb = b2[tl * 16 + c0];
        f32x4 ci = {bb, bb, bb, bb};
        f16x8 bw = *(const f16x8*)(w2t + (tl * 16 + c0) * 32 + kg * 8);
        oc[tl] = __builtin_amdgcn_mfma_f32_16x16x32_f16(ah, bw, ci, 0, 0, 0);
    }

    // ---- row L2 normalize + coalesced stores ----
    #pragma unroll
    for (int i = 0; i < 4; ++i) {
        float ss = oc[0][i] * oc[0][i] + oc[1][i] * oc[1][i]
                 + oc[2][i] * oc[2][i] + oc[3][i] * oc[3][i];
        ss += __shfl_xor(ss, 1); ss += __shfl_xor(ss, 2);
        ss += __shfl_xor(ss, 4); ss += __shfl_xor(ss, 8);
        float sc = 1.0f / fmaxf(sqrtf(ss), 1e-12f);
        int row = gr0 + kg * 4 + i;
        if (row < N) {
            #pragma unroll
            for (int tl = 0; tl < 4; ++tl)
                h0[(size_t)row * DD + tl * 16 + c0] = oc[tl][i] * sc;
        }
    }
}

// ---------------------------------------------------------------------------
// Graph build, one edge read: bin into 64 queues (cohort p = c/cw, writer
// class w8 = blockIdx&7 => queue tail stays XCD-local). Entry = r | c_local<<17.
// ---------------------------------------------------------------------------
__global__ void zero_k(int* __restrict__ p, int n)
{
    int i = blockIdx.x * blockDim.x + threadIdx.x;
    int stride = gridDim.x * blockDim.x;
    for (; i < n; i += stride) p[i] = 0;
}

__global__ __launch_bounds__(256)
void binq_k(const int* __restrict__ erow, const int* __restrict__ ecol, int M,
            unsigned* __restrict__ queue, int* __restrict__ qcnt, int cw)
{
    const int w8 = blockIdx.x & 7;
    const int lane = threadIdx.x & 63;
    int i = blockIdx.x * 256 + threadIdx.x;
    const int stride = gridDim.x * 256;
    for (; i < M; i += stride) {
        int c = ecol[i];
        int r = erow[i];
        int p = c / cw;
        unsigned pk = (unsigned)r | ((unsigned)(c - p * cw) << 17);
        #pragma unroll
        for (int pp = 0; pp < 8; ++pp) {
            unsigned long long m = __ballot(p == pp);
            if (p == pp) {
                int cnt_ = __popcll(m);
                int rank = __popcll(m & ((1ull << lane) - 1ull));
                int leader = __ffsll((long long)m) - 1;
                int base = 0;
                if (rank == 0) base = atomicAdd(&qcnt[pp * 8 + w8], cnt_);
                base = __shfl(base, leader);
                queue[(size_t)(pp * 8 + w8) * QCAP + base + rank] = pk;
            }
        }
    }
}

__global__ __launch_bounds__(256)
void countq_k(const unsigned* __restrict__ queue, const int* __restrict__ qcnt,
              int* __restrict__ cnt, int cw)
{
    const int p = blockIdx.x & 7;
    const int crank = blockIdx.x >> 3;
    const int cstride = (gridDim.x >> 3) * 256;
    int* cbase = cnt + p * cw;
    #pragma unroll 1
    for (int sq = 0; sq < 8; ++sq) {
        int n = qcnt[p * 8 + sq];
        const unsigned* q = queue + (size_t)(p * 8 + sq) * QCAP;
        for (int i = crank * 256 + threadIdx.x; i < n; i += cstride)
            atomicAdd(&cbase[q[i] >> 17], 1);
    }
}

__global__ __launch_bounds__(256)
void scan_dinv_k(const int* __restrict__ cnt, int* __restrict__ start,
                 float* __restrict__ dinv, int* __restrict__ gctr, int N)
{
    __shared__ int sd[256];
    __shared__ int sbase;
    int t = threadIdx.x;
    int v = blockIdx.x * 256 + t;
    int c = (v < N) ? cnt[v] : 0;
    sd[t] = c;
    __syncthreads();
    #pragma unroll
    for (int off = 1; off < 256; off <<= 1) {
        int tmp = (t >= off) ? sd[t - off] : 0;
        __syncthreads();
        sd[t] += tmp;
        __syncthreads();
    }
    int incl = sd[t];
    if (t == 255) sbase = atomicAdd(gctr, sd[255]);
    __syncthreads();
    if (v < N) {
        start[v] = sbase + incl - c;
        dinv[v]  = (c > 0) ? rsqrtf((float)c) : 0.0f;
    }
}

__global__ __launch_bounds__(256)
void fillq_k(const unsigned* __restrict__ queue, const int* __restrict__ qcnt,
             const int* __restrict__ start, int* __restrict__ cursor,
             int* __restrict__ csr_src, int cw)
{
    const int p = blockIdx.x & 7;
    const int crank = blockIdx.x >> 3;
    const int cstride = (gridDim.x >> 3) * 256;
    #pragma unroll 1
    for (int sq = 0; sq < 8; ++sq) {
        int n = qcnt[p * 8 + sq];
        const unsigned* q = queue + (size_t)(p * 8 + sq) * QCAP;
        for (int i = crank * 256 + threadIdx.x; i < n; i += cstride) {
            unsigned pk = q[i];
            int c = p * cw + (int)(pk >> 17);
            int pos = start[c] + atomicAdd(&cursor[c], 1);
            csr_src[pos] = (int)(pk & 0x1FFFFu);
        }
    }
}

// ---------------------------------------------------------------------------
// mirror[v][d] = dinv[v] * h[v][d] as fp16
// ---------------------------------------------------------------------------
__global__ __launch_bounds__(256)
void mkmir_k(const float* __restrict__ h, const float* __restrict__ dinv,
             h16* __restrict__ m, int N)
{
    int i = blockIdx.x * 256 + threadIdx.x;
    if (i >= N * 32) return;
    float2 v = ((const float2*)h)[i];
    float dv = dinv[i >> 5];
    h16 a = (h16)(v.x * dv);
    h16 b = (h16)(v.y * dv);
    unsigned short ua = *(unsigned short*)&a;
    unsigned short ub = *(unsigned short*)&b;
    ((unsigned int*)m)[i] = (unsigned)ua | ((unsigned)ub << 16);
}

// ---------------------------------------------------------------------------
// Propagation: wave per node. hout[v] = dinv[v] * sum_r mirror[r]
// ---------------------------------------------------------------------------
__global__ __launch_bounds__(256)
void prop16_k(const h16* __restrict__ min_, float* __restrict__ hout,
              h16* __restrict__ mout,
              const int* __restrict__ start, const int* __restrict__ cnt,
              const int* __restrict__ csr_src, const float* __restrict__ dinv, int N)
{
    int v = blockIdx.x * 4 + (threadIdx.x >> 6);
    int lane = threadIdx.x & 63;
    if (v >= N) return;
    int s = start[v];
    int e = s + cnt[v];
    float dv = dinv[v];
    float acc = 0.0f;
    int i = s;
    for (; i + 3 < e; i += 4) {
        int r0 = csr_src[i],     r1 = csr_src[i + 1];
        int r2 = csr_src[i + 2], r3 = csr_src[i + 3];
        float v0 = (float)min_[(size_t)r0 * DD + lane];
        float v1 = (float)min_[(size_t)r1 * DD + lane];
        float v2 = (float)min_[(size_t)r2 * DD + lane];
        float v3 = (float)min_[(size_t)r3 * DD + lane];
        acc += v0 + v1 + v2 + v3;
    }
    for (; i < e; ++i) {
        int r = csr_src[i];
        acc += (float)min_[(size_t)r * DD + lane];
    }
    float res = dv * acc;
    hout[(size_t)v * DD + lane] = res;
    if (mout) mout[(size_t)v * DD + lane] = (h16)(dv * res);
}

// ---------------------------------------------------------------------------
extern "C" void kernel_launch(void* const* d_in, const int* in_sizes, int n_in,
                              void* d_out, int out_size, void* d_ws, size_t ws_size,
                              hipStream_t stream)
{
    const float* x     = (const float*)d_in[0];
    const int*   ei    = (const int*)  d_in[1];
    const float* W1    = (const float*)d_in[2];
    const float* b1    = (const float*)d_in[3];
    const float* gamma = (const float*)d_in[4];
    const float* beta  = (const float*)d_in[5];
    const float* W2    = (const float*)d_in[6];
    const float* b2    = (const float*)d_in[7];
    float* out = (float*)d_out;

    const int N = in_sizes[0] / F_IN;       // 100000
    const int M = in_sizes[1] / 2;          // 3300000
    const int cw = (N + 7) / 8;             // cohort width (12500)
    const int* erow = ei;
    const int* ecol = ei + M;

    // workspace layout (ints)
    int* wsI = (int*)d_ws;
    int*   cnt     = wsI;                   // N
    int*   cursor  = wsI + N;               // N
    int*   gctr    = wsI + 2 * N;           // 1 (+3 pad)
    int*   qcnt    = wsI + 2 * N + 4;       // 64
    int*   startv  = wsI + 2 * N + 68;      // N
    float* dinv    = (float*)(wsI + 3 * N + 68);  // N
    h16*   w1t     = (h16*)(wsI + 4 * N + 68);    // 32*512 f16 = 8192 ints
    h16*   w2t     = (h16*)(wsI + 4 * N + 68 + 8192);  // 1024 ints
    int*   csr_src = wsI + 4 * N + 68 + 9216;     // M
    unsigned* queue = (unsigned*)(csr_src + M);   // 64*QCAP u32 (25.6MB)
    h16*   mir0    = (h16*)queue;                 // overlays queue (dead after fillq)
    h16*   mir1    = mir0 + (size_t)N * DD;

    zero_k<<<512, 256, 0, stream>>>(wsI, 2 * N + 68);
    prep_k<<<(32 * 512 + 64 * 32 + 255) / 256, 256, 0, stream>>>(W1, W2, w1t, w2t);

    encoder_k<<<(N + 63) / 64, 256, 0, stream>>>(x, w1t, b1, gamma, beta, w2t, b2, out, N);

    binq_k<<<2048, 256, 0, stream>>>(erow, ecol, M, queue, qcnt, cw);
    countq_k<<<2048, 256, 0, stream>>>(queue, qcnt, cnt, cw);
    scan_dinv_k<<<(N + 255) / 256, 256, 0, stream>>>(cnt, startv, dinv, gctr, N);
    fillq_k<<<2048, 256, 0, stream>>>(queue, qcnt, startv, cursor, csr_src, cw);

    float* h0 = out;
    float* h1 = out + (size_t)N * DD;
    float* h2 = out + 2 * (size_t)N * DD;

    mkmir_k<<<(N * 32 + 255) / 256, 256, 0, stream>>>(h0, dinv, mir0, N);
    prop16_k<<<(N + 3) / 4, 256, 0, stream>>>(mir0, h1, mir1, startv, cnt, csr_src, dinv, N);
    prop16_k<<<(N + 3) / 4, 256, 0, stream>>>(mir1, h2, (h16*)nullptr, startv, cnt, csr_src, dinv, N);
}

// Round 7
// 675.524 us; speedup vs baseline: 4.0351x; 4.0351x over previous
//
#include <hip/hip_runtime.h>

#define F_IN 500
#define HH 32
#define DD 64
#define LN_EPS 1e-6f
#define QCAP 100000     // slots per (cohort, writer-class) queue
#define SPAN 4096       // edges per wave in binq (atomic amortization)

typedef float f32x4 __attribute__((ext_vector_type(4)));
typedef _Float16 f16x8 __attribute__((ext_vector_type(8)));
typedef _Float16 h16;

// ---------------------------------------------------------------------------
// prep: W1T f16 [32 j][512 k] (zero-padded k>=500), W2T f16 [64 d][32 j]
// ---------------------------------------------------------------------------
__global__ __launch_bounds__(256)
void prep_k(const float* __restrict__ W1, const float* __restrict__ W2,
            h16* __restrict__ w1t, h16* __restrict__ w2t)
{
    int i = blockIdx.x * 256 + threadIdx.x;
    if (i < 32 * 512) {
        int j = i >> 9, k = i & 511;
        w1t[i] = (k < F_IN) ? (h16)W1[k * HH + j] : (h16)0.f;
    }
    int i2 = i - 32 * 512;
    if (i2 >= 0 && i2 < 64 * 32) {
        int d = i2 >> 5, j = i2 & 31;
        w2t[i2] = (h16)W2[j * DD + d];
    }
}

// ---------------------------------------------------------------------------
// Encoder via MFMA 16x16x32 f16 (round-6, verified absmax 3.9e-3).
// ---------------------------------------------------------------------------
__global__ __launch_bounds__(256)
void encoder_k(const float* __restrict__ x,
               const h16* __restrict__ w1t, const float* __restrict__ b1,
               const float* __restrict__ gamma, const float* __restrict__ beta,
               const h16* __restrict__ w2t, const float* __restrict__ b2,
               float* __restrict__ h0, int N)
{
    __shared__ h16 hbuf[4][512];

    const int t = threadIdx.x;
    const int w = t >> 6, l = t & 63;
    const int c0 = l & 15, kg = l >> 4;
    const int gr0 = (blockIdx.x * 4 + w) * 16;
    int rowA = gr0 + c0; if (rowA >= N) rowA = N - 1;
    const float* xr = x + (size_t)rowA * F_IN;

    float b1a = b1[c0], b1b = b1[c0 + 16];
    f32x4 acc0 = {b1a, b1a, b1a, b1a};
    f32x4 acc1 = {b1b, b1b, b1b, b1b};

    const h16* w1a = w1t + c0 * 512 + kg * 8;
    const h16* w1b = w1a + 16 * 512;

    #pragma unroll 3
    for (int ks = 0; ks < 15; ++ks) {
        const int k0 = ks * 32;
        f32x4 xa = *(const f32x4*)(xr + k0 + kg * 8);
        f32x4 xb = *(const f32x4*)(xr + k0 + kg * 8 + 4);
        f16x8 af;
        af[0] = (h16)xa[0]; af[1] = (h16)xa[1]; af[2] = (h16)xa[2]; af[3] = (h16)xa[3];
        af[4] = (h16)xb[0]; af[5] = (h16)xb[1]; af[6] = (h16)xb[2]; af[7] = (h16)xb[3];
        f16x8 bf0 = *(const f16x8*)(w1a + k0);
        f16x8 bf1 = *(const f16x8*)(w1b + k0);
        acc0 = __builtin_amdgcn_mfma_f32_16x16x32_f16(af, bf0, acc0, 0, 0, 0);
        acc1 = __builtin_amdgcn_mfma_f32_16x16x32_f16(af, bf1, acc1, 0, 0, 0);
    }
    {
        f16x8 af;
        #pragma unroll
        for (int e = 0; e < 8; ++e) {
            int k = 480 + kg * 8 + e;
            af[e] = (k < F_IN) ? (h16)xr[k] : (h16)0.f;
        }
        f16x8 bf0 = *(const f16x8*)(w1a + 480);
        f16x8 bf1 = *(const f16x8*)(w1b + 480);
        acc0 = __builtin_amdgcn_mfma_f32_16x16x32_f16(af, bf0, acc0, 0, 0, 0);
        acc1 = __builtin_amdgcn_mfma_f32_16x16x32_f16(af, bf1, acc1, 0, 0, 0);
    }

    float g0 = gamma[c0], g1 = gamma[c0 + 16];
    float be0 = beta[c0], be1 = beta[c0 + 16];
    h16* hb = hbuf[w];
    #pragma unroll
    for (int i = 0; i < 4; ++i) {
        float a0 = acc0[i], a1 = acc1[i];
        float s = a0 + a1;
        s += __shfl_xor(s, 1); s += __shfl_xor(s, 2);
        s += __shfl_xor(s, 4); s += __shfl_xor(s, 8);
        float mu = s * (1.0f / 32.0f);
        float d0 = a0 - mu, d1 = a1 - mu;
        float vv = d0 * d0 + d1 * d1;
        vv += __shfl_xor(vv, 1); vv += __shfl_xor(vv, 2);
        vv += __shfl_xor(vv, 4); vv += __shfl_xor(vv, 8);
        float is = rsqrtf(vv * (1.0f / 32.0f) + LN_EPS);
        float h0v = fmaxf(fmaf(d0 * is, g0, be0), 0.f);
        float h1v = fmaxf(fmaf(d1 * is, g1, be1), 0.f);
        int r = kg * 4 + i;
        hb[r * 32 + ((((c0 >> 3) ^ i) & 3) << 3) + (c0 & 7)] = (h16)h0v;
        hb[r * 32 + ((((2 + (c0 >> 3)) ^ i) & 3) << 3) + (c0 & 7)] = (h16)h1v;
    }
    asm volatile("s_waitcnt lgkmcnt(0)" ::: "memory");
    __builtin_amdgcn_sched_barrier(0);

    f16x8 ah = *(const f16x8*)(hb + c0 * 32 + (((kg ^ (c0 & 3)) & 3) << 3));

    f32x4 oc[4];
    #pragma unroll
    for (int tl = 0; tl < 4; ++tl) {
        float bb = b2[tl * 16 + c0];
        f32x4 ci = {bb, bb, bb, bb};
        f16x8 bw = *(const f16x8*)(w2t + (tl * 16 + c0) * 32 + kg * 8);
        oc[tl] = __builtin_amdgcn_mfma_f32_16x16x32_f16(ah, bw, ci, 0, 0, 0);
    }

    #pragma unroll
    for (int i = 0; i < 4; ++i) {
        float ss = oc[0][i] * oc[0][i] + oc[1][i] * oc[1][i]
                 + oc[2][i] * oc[2][i] + oc[3][i] * oc[3][i];
        ss += __shfl_xor(ss, 1); ss += __shfl_xor(ss, 2);
        ss += __shfl_xor(ss, 4); ss += __shfl_xor(ss, 8);
        float sc = 1.0f / fmaxf(sqrtf(ss), 1e-12f);
        int row = gr0 + kg * 4 + i;
        if (row < N) {
            #pragma unroll
            for (int tl = 0; tl < 4; ++tl)
                h0[(size_t)row * DD + tl * 16 + c0] = oc[tl][i] * sc;
        }
    }
}

// ---------------------------------------------------------------------------
__global__ void zero_k(int* __restrict__ p, int n)
{
    int i = blockIdx.x * blockDim.x + threadIdx.x;
    int stride = gridDim.x * blockDim.x;
    for (; i < n; i += stride) p[i] = 0;
}

// ---------------------------------------------------------------------------
// binq v2: wave-autonomous two-pass span binner. Wave owns SPAN contiguous
// edges. Pass1: register cohort histogram -> butterfly reduce -> ONE 8-lane
// atomicAdd reserves all 8 queue bases (6.4K atomic-lane-ops total vs 412K
// in v1). Pass2: re-read span (cache-hot), ballot-rank scatter, zero atomics.
// ---------------------------------------------------------------------------
__global__ __launch_bounds__(256)
void binq_k(const int* __restrict__ erow, const int* __restrict__ ecol, int M,
            unsigned* __restrict__ queue, int* __restrict__ qcnt,
            int cw, unsigned magic)
{
    const int wid  = blockIdx.x * 4 + (threadIdx.x >> 6);
    const int lane = threadIdx.x & 63;
    const int nw   = gridDim.x * 4;
    const int cls  = blockIdx.x & 7;

    for (int s0 = wid * SPAN; s0 < M; s0 += nw * SPAN) {
        const int e1 = min(s0 + SPAN, M);
        // ---- pass 1: count cohorts in registers ----
        int tc[8] = {0, 0, 0, 0, 0, 0, 0, 0};
        for (int i = s0 + lane; i < e1; i += 64) {
            int c = ecol[i];
            unsigned p = (unsigned)(((unsigned long long)(unsigned)c * magic) >> 32);
            #pragma unroll
            for (int pp = 0; pp < 8; ++pp) tc[pp] += (p == (unsigned)pp) ? 1 : 0;
        }
        #pragma unroll
        for (int pp = 0; pp < 8; ++pp) {
            #pragma unroll
            for (int m = 1; m < 64; m <<= 1) tc[pp] += __shfl_xor(tc[pp], m);
        }
        // one atomic instruction, lanes 0..7 reserve their cohort's space
        int val = tc[0];
        #pragma unroll
        for (int pp = 1; pp < 8; ++pp) val = (lane == pp) ? tc[pp] : val;
        int base = 0;
        if (lane < 8) base = atomicAdd(&qcnt[lane * 8 + cls], val);
        int bases[8], run[8];
        #pragma unroll
        for (int pp = 0; pp < 8; ++pp) { bases[pp] = __shfl(base, pp); run[pp] = 0; }

        // ---- pass 2: ballot-rank scatter (span is L1/L2-hot) ----
        for (int i0 = s0; i0 < e1; i0 += 64) {
            int i = i0 + lane;
            bool act = i < e1;
            int c = act ? ecol[i] : 0;
            int r = act ? erow[i] : 0;
            unsigned p = act ? (unsigned)(((unsigned long long)(unsigned)c * magic) >> 32)
                             : 0xFFu;
            unsigned pk = (unsigned)r | ((unsigned)(c - (int)p * cw) << 17);
            #pragma unroll
            for (int pp = 0; pp < 8; ++pp) {
                unsigned long long mm = __ballot(p == (unsigned)pp);
                if (p == (unsigned)pp) {
                    int rank = __popcll(mm & ((1ull << lane) - 1ull));
                    queue[(size_t)(pp * 8 + cls) * QCAP + bases[pp] + run[pp] + rank] = pk;
                }
                run[pp] += (int)__popcll(mm);
            }
        }
    }
}

__global__ __launch_bounds__(256)
void countq_k(const unsigned* __restrict__ queue, const int* __restrict__ qcnt,
              int* __restrict__ cnt, int cw)
{
    const int p = blockIdx.x & 7;
    const int crank = blockIdx.x >> 3;
    const int cstride = (gridDim.x >> 3) * 256;
    int* cbase = cnt + p * cw;
    #pragma unroll 1
    for (int sq = 0; sq < 8; ++sq) {
        int n = qcnt[p * 8 + sq];
        const unsigned* q = queue + (size_t)(p * 8 + sq) * QCAP;
        for (int i = crank * 256 + threadIdx.x; i < n; i += cstride)
            atomicAdd(&cbase[q[i] >> 17], 1);
    }
}

__global__ __launch_bounds__(256)
void scan_dinv_k(const int* __restrict__ cnt, int* __restrict__ start,
                 float* __restrict__ dinv, int* __restrict__ gctr, int N)
{
    __shared__ int sd[256];
    __shared__ int sbase;
    int t = threadIdx.x;
    int v = blockIdx.x * 256 + t;
    int c = (v < N) ? cnt[v] : 0;
    sd[t] = c;
    __syncthreads();
    #pragma unroll
    for (int off = 1; off < 256; off <<= 1) {
        int tmp = (t >= off) ? sd[t - off] : 0;
        __syncthreads();
        sd[t] += tmp;
        __syncthreads();
    }
    int incl = sd[t];
    if (t == 255) sbase = atomicAdd(gctr, sd[255]);
    __syncthreads();
    if (v < N) {
        start[v] = sbase + incl - c;
        dinv[v]  = (c > 0) ? rsqrtf((float)c) : 0.0f;
    }
}

__global__ __launch_bounds__(256)
void fillq_k(const unsigned* __restrict__ queue, const int* __restrict__ qcnt,
             const int* __restrict__ start, int* __restrict__ cursor,
             int* __restrict__ csr_src, int cw)
{
    const int p = blockIdx.x & 7;
    const int crank = blockIdx.x >> 3;
    const int cstride = (gridDim.x >> 3) * 256;
    #pragma unroll 1
    for (int sq = 0; sq < 8; ++sq) {
        int n = qcnt[p * 8 + sq];
        const unsigned* q = queue + (size_t)(p * 8 + sq) * QCAP;
        for (int i = crank * 256 + threadIdx.x; i < n; i += cstride) {
            unsigned pk = q[i];
            int c = p * cw + (int)(pk >> 17);
            int pos = start[c] + atomicAdd(&cursor[c], 1);
            csr_src[pos] = (int)(pk & 0x1FFFFu);
        }
    }
}

// ---------------------------------------------------------------------------
__global__ __launch_bounds__(256)
void mkmir_k(const float* __restrict__ h, const float* __restrict__ dinv,
             h16* __restrict__ m, int N)
{
    int i = blockIdx.x * 256 + threadIdx.x;
    if (i >= N * 32) return;
    float2 v = ((const float2*)h)[i];
    float dv = dinv[i >> 5];
    h16 a = (h16)(v.x * dv);
    h16 b = (h16)(v.y * dv);
    unsigned short ua = *(unsigned short*)&a;
    unsigned short ub = *(unsigned short*)&b;
    ((unsigned int*)m)[i] = (unsigned)ua | ((unsigned)ub << 16);
}

__global__ __launch_bounds__(256)
void prop16_k(const h16* __restrict__ min_, float* __restrict__ hout,
              h16* __restrict__ mout,
              const int* __restrict__ start, const int* __restrict__ cnt,
              const int* __restrict__ csr_src, const float* __restrict__ dinv, int N)
{
    int v = blockIdx.x * 4 + (threadIdx.x >> 6);
    int lane = threadIdx.x & 63;
    if (v >= N) return;
    int s = start[v];
    int e = s + cnt[v];
    float dv = dinv[v];
    float acc = 0.0f;
    int i = s;
    for (; i + 3 < e; i += 4) {
        int r0 = csr_src[i],     r1 = csr_src[i + 1];
        int r2 = csr_src[i + 2], r3 = csr_src[i + 3];
        float v0 = (float)min_[(size_t)r0 * DD + lane];
        float v1 = (float)min_[(size_t)r1 * DD + lane];
        float v2 = (float)min_[(size_t)r2 * DD + lane];
        float v3 = (float)min_[(size_t)r3 * DD + lane];
        acc += v0 + v1 + v2 + v3;
    }
    for (; i < e; ++i) {
        int r = csr_src[i];
        acc += (float)min_[(size_t)r * DD + lane];
    }
    float res = dv * acc;
    hout[(size_t)v * DD + lane] = res;
    if (mout) mout[(size_t)v * DD + lane] = (h16)(dv * res);
}

// ---------------------------------------------------------------------------
extern "C" void kernel_launch(void* const* d_in, const int* in_sizes, int n_in,
                              void* d_out, int out_size, void* d_ws, size_t ws_size,
                              hipStream_t stream)
{
    const float* x     = (const float*)d_in[0];
    const int*   ei    = (const int*)  d_in[1];
    const float* W1    = (const float*)d_in[2];
    const float* b1    = (const float*)d_in[3];
    const float* gamma = (const float*)d_in[4];
    const float* beta  = (const float*)d_in[5];
    const float* W2    = (const float*)d_in[6];
    const float* b2    = (const float*)d_in[7];
    float* out = (float*)d_out;

    const int N = in_sizes[0] / F_IN;       // 100000
    const int M = in_sizes[1] / 2;          // 3300000
    const int cw = (N + 7) / 8;             // 12500
    const unsigned magic = (unsigned)((0x100000000ULL + cw - 1) / cw);
    const int* erow = ei;
    const int* ecol = ei + M;

    // workspace layout (ints)
    int* wsI = (int*)d_ws;
    int*   cnt     = wsI;                   // N
    int*   cursor  = wsI + N;               // N
    int*   gctr    = wsI + 2 * N;           // 4
    int*   qcnt    = wsI + 2 * N + 4;       // 64
    int*   startv  = wsI + 2 * N + 68;      // N
    float* dinv    = (float*)(wsI + 3 * N + 68);        // N
    h16*   w1t     = (h16*)(wsI + 4 * N + 68);          // 8192 ints
    h16*   w2t     = (h16*)(wsI + 4 * N + 68 + 8192);   // 1024 ints
    int*   csr_src = wsI + 4 * N + 68 + 9216;           // M
    unsigned* queue = (unsigned*)(csr_src + M);         // 64*QCAP
    h16*   mir0    = (h16*)queue;                       // overlays queue
    h16*   mir1    = mir0 + (size_t)N * DD;

    zero_k<<<512, 256, 0, stream>>>(wsI, 2 * N + 68);
    prep_k<<<(32 * 512 + 64 * 32 + 255) / 256, 256, 0, stream>>>(W1, W2, w1t, w2t);

    encoder_k<<<(N + 63) / 64, 256, 0, stream>>>(x, w1t, b1, gamma, beta, w2t, b2, out, N);

    binq_k<<<256, 256, 0, stream>>>(erow, ecol, M, queue, qcnt, cw, magic);
    countq_k<<<2048, 256, 0, stream>>>(queue, qcnt, cnt, cw);
    scan_dinv_k<<<(N + 255) / 256, 256, 0, stream>>>(cnt, startv, dinv, gctr, N);
    fillq_k<<<2048, 256, 0, stream>>>(queue, qcnt, startv, cursor, csr_src, cw);

    float* h0 = out;
    float* h1 = out + (size_t)N * DD;
    float* h2 = out + 2 * (size_t)N * DD;

    mkmir_k<<<(N * 32 + 255) / 256, 256, 0, stream>>>(h0, dinv, mir0, N);
    prop16_k<<<(N + 3) / 4, 256, 0, stream>>>(mir0, h1, mir1, startv, cnt, csr_src, dinv, N);
    prop16_k<<<(N + 3) / 4, 256, 0, stream>>>(mir1, h2, (h16*)nullptr, startv, cnt, csr_src, dinv, N);
}